// Round 1
// baseline (258.243 us; speedup 1.0000x reference)
//
#include <hip/hip_runtime.h>
#include <hip/hip_bf16.h>

#define NN 4
#define LL 8192
#define HH 8
#define DD 64
#define NH 32                 // n*h combos
#define RS  (HH*DD)           // 512 floats between consecutive s rows
#define KV_ELEMS 4160         // 64x64 partial kvT [d][m] + ksum[d]
#define CCH 32                // C-kernel chunks per nh

typedef __attribute__((ext_vector_type(8))) short bf16x8;   // 8 bf16 (4 VGPR)
typedef __attribute__((ext_vector_type(4))) float f32x4;    // acc / vec loads

__device__ __forceinline__ float phi(float x) {
  // elu(x*temp) + 1 ; temp = 64^(-0.25)
  float t = x * 0.35355339059327373f;
  return t > 0.f ? t + 1.f : __expf(t);
}
__device__ __forceinline__ short f2bf(float x) {
  __hip_bfloat16 h = __float2bfloat16(x);                  // RN
  return (short)__builtin_bit_cast(unsigned short, h);
}
__device__ __forceinline__ float bf2f(short s) {
  __hip_bfloat16 h = __builtin_bit_cast(__hip_bfloat16, (unsigned short)s);
  return __bfloat162float(h);
}
// split fp32 -> hi + lo bf16 (combined ~16-bit mantissa)
__device__ __forceinline__ void split2(float x, short& hi, short& lo) {
  hi = f2bf(x);
  lo = f2bf(x - bf2f(hi));
}
__device__ __forceinline__ int pk2(short a, short b) {
  return (int)(((unsigned)(unsigned short)a) | (((unsigned)(unsigned short)b) << 16));
}
#define MFMA16 __builtin_amdgcn_mfma_f32_16x16x32_bf16

// ---------------- Kernel A: partial kvT[d][m] += phi(K)^T V over s-chunk ----------------
// v2: coalesced float4 global loads (Little's-law fix: 16B transactions instead of
// 4B at 2KB stride), LDS-transposed hi/lo bf16 planes [d][s] (pitch 72 shorts =
// 144B -> uniform bank spread on b64 writes and b128 frag reads), next-tile
// loads issued before the MFMA phase. Same 3-mfma split scheme and D layout.
__global__ __launch_bounds__(256, 4) void kv_partial_kernel(
    const float* __restrict__ K, const float* __restrict__ V,
    float* __restrict__ part, int sch)
{
  const int nh    = blockIdx.x / sch;
  const int chunk = blockIdx.x % sch;
  const int n = nh >> 3, h = nh & 7;
  const int tid = threadIdx.x;
  const int w = tid >> 6, lane = tid & 63;
  const int q = lane >> 4, p = lane & 15;
  const int dsup = (w >> 1) * 32, msup = (w & 1) * 32;
  const int g = tid >> 4, c = tid & 15;          // staging roles: rows 4g+u, cols 4c..4c+3
  const int rows_pb = LL / sch;
  const int ntiles  = rows_pb / 64;
  const int s_base  = chunk * rows_pb;

  const float* kbase = K + ((size_t)n * LL * HH + h) * DD;
  const float* vbase = V + ((size_t)n * LL * HH + h) * DD;

  // planes: 0=K.hi 1=K.lo 2=V.hi 3=V.lo ; [d][s] transposed, 8-short pad
  __shared__ __align__(16) short lds4[4][64][72];

  f32x4 acc[2][2] = {};
  float ksp[4] = {0.f, 0.f, 0.f, 0.f};
  f32x4 kf[4], vf[4];

#define LOADT(T) { \
    const float* kp_ = kbase + (size_t)(s_base + (T) * 64 + 4 * g) * RS + 4 * c; \
    const float* vp_ = vbase + (size_t)(s_base + (T) * 64 + 4 * g) * RS + 4 * c; \
    kf[0] = *(const f32x4*)(kp_);          vf[0] = *(const f32x4*)(vp_); \
    kf[1] = *(const f32x4*)(kp_ + RS);     vf[1] = *(const f32x4*)(vp_ + RS); \
    kf[2] = *(const f32x4*)(kp_ + 2*RS);   vf[2] = *(const f32x4*)(vp_ + 2*RS); \
    kf[3] = *(const f32x4*)(kp_ + 3*RS);   vf[3] = *(const f32x4*)(vp_ + 3*RS); }

  LOADT(0);

  for (int tile = 0; tile < ntiles; ++tile) {
    // ---- stage: phi + hi/lo split + pack, write transposed [d][s] ----
#pragma unroll
    for (int j = 0; j < 4; ++j) {
      short sh[4], sl[4];
#pragma unroll
      for (int u = 0; u < 4; ++u) {
        float f = phi(kf[u][j]);
        ksp[j] += f;
        split2(f, sh[u], sl[u]);
      }
      *(int2*)&lds4[0][4*c + j][4*g] = make_int2(pk2(sh[0], sh[1]), pk2(sh[2], sh[3]));
      *(int2*)&lds4[1][4*c + j][4*g] = make_int2(pk2(sl[0], sl[1]), pk2(sl[2], sl[3]));
#pragma unroll
      for (int u = 0; u < 4; ++u) split2(vf[u][j], sh[u], sl[u]);
      *(int2*)&lds4[2][4*c + j][4*g] = make_int2(pk2(sh[0], sh[1]), pk2(sh[2], sh[3]));
      *(int2*)&lds4[3][4*c + j][4*g] = make_int2(pk2(sl[0], sl[1]), pk2(sl[2], sl[3]));
    }
    __syncthreads();

    if (tile + 1 < ntiles) LOADT(tile + 1);     // overlap next loads with MFMA phase

    // ---- fragments + 3-mfma split per tile-pair ----
#pragma unroll
    for (int ks = 0; ks < 2; ++ks) {
      const int so = ks * 32 + q * 8;
      bf16x8 ah[2], al[2], bh[2], bl[2];
#pragma unroll
      for (int dt = 0; dt < 2; ++dt) {
        ah[dt] = *(const bf16x8*)&lds4[0][dsup + dt * 16 + p][so];
        al[dt] = *(const bf16x8*)&lds4[1][dsup + dt * 16 + p][so];
      }
#pragma unroll
      for (int mt = 0; mt < 2; ++mt) {
        bh[mt] = *(const bf16x8*)&lds4[2][msup + mt * 16 + p][so];
        bl[mt] = *(const bf16x8*)&lds4[3][msup + mt * 16 + p][so];
      }
#pragma unroll
      for (int dt = 0; dt < 2; ++dt)
#pragma unroll
        for (int mt = 0; mt < 2; ++mt) {
          acc[dt][mt] = MFMA16(ah[dt], bh[mt], acc[dt][mt], 0, 0, 0);
          acc[dt][mt] = MFMA16(ah[dt], bl[mt], acc[dt][mt], 0, 0, 0);
          acc[dt][mt] = MFMA16(al[dt], bh[mt], acc[dt][mt], 0, 0, 0);
        }
    }
    __syncthreads();
  }
#undef LOADT

  // ---- store partial: D layout col=lane&15, row=quad*4+reg ----
  float* po = part + (size_t)blockIdx.x * KV_ELEMS;
#pragma unroll
  for (int dt = 0; dt < 2; ++dt)
#pragma unroll
    for (int mt = 0; mt < 2; ++mt) {
      const int row = dsup + dt * 16 + q * 4;
      const int col = msup + mt * 16 + p;
#pragma unroll
      for (int r = 0; r < 4; ++r)
        po[(row + r) * 64 + col] = acc[dt][mt][r];
    }

  // ---- ksum: per-thread partials (d=4c+j over rows 4g+u of all tiles) -> LDS reduce ----
  float* ksl = (float*)lds4;                     // 256*4 floats, reuse (barrier above)
  f32x4 kq = {ksp[0], ksp[1], ksp[2], ksp[3]};
  *(f32x4*)&ksl[tid * 4] = kq;
  __syncthreads();
  if (tid < 64) {
    float s = 0.f;
#pragma unroll
    for (int gg = 0; gg < 16; ++gg)
      s += ksl[(gg * 16 + (tid >> 2)) * 4 + (tid & 3)];
    po[4096 + tid] = s;
  }
}

// ---------------- Kernel B: reduce partials; emit kv m-major split hi/lo + ksum ----------------
__global__ __launch_bounds__(256) void kv_reduce_kernel(
    const float* __restrict__ part, short* __restrict__ kvh,
    short* __restrict__ kvl, float* __restrict__ ksum, int np)
{
  const int nh = blockIdx.x / 17;
  const int e  = (blockIdx.x % 17) * 256 + threadIdx.x;
  if (e >= KV_ELEMS) return;
  const float* pp = part + (size_t)nh * np * KV_ELEMS + e;
  float s = 0.f;
  for (int i = 0; i < np; ++i) s += pp[(size_t)i * KV_ELEMS];
  if (e < 4096) {
    const int d = e >> 6, m = e & 63;
    short hi, lo; split2(s, hi, lo);
    kvh[(size_t)nh * 4096 + m * 64 + d] = hi;     // m-major: C's B-frags read
    kvl[(size_t)nh * 4096 + m * 64 + d] = lo;     // contiguous d-runs
  } else {
    ksum[(size_t)nh * 64 + (e - 4096)] = s;
  }
}

// ---------------- Kernel C: out[l][m] = z_l * (phi(Q) . kvT) via MFMA ----------------
// wave w: m_super=(w&1)*32, row-half=(w>>1). kv B-frags resident in registers
// (8 frags = 32 VGPR); A frags built from global Q (d-contiguous); z on VALU.
__global__ __launch_bounds__(256) void attn_out_kernel(
    const float* __restrict__ Q, const short* __restrict__ kvh,
    const short* __restrict__ kvl, const float* __restrict__ ksumg,
    float* __restrict__ out)
{
  const int nh    = blockIdx.x / CCH;
  const int chunk = blockIdx.x % CCH;
  const int n = nh >> 3, h = nh & 7;
  const int tid = threadIdx.x;
  const int w = tid >> 6, lane = tid & 63;
  const int q = lane >> 4, p = lane & 15;
  const int m_super = (w & 1) * 32;
  const int rows_pb = LL / CCH;                       // 256
  const int row_base = chunk * rows_pb + (w >> 1) * (rows_pb / 2);

  const float* qbase = Q + ((size_t)n * LL * HH + h) * DD;

  // resident B frags: B[k=d = kst*32+q*8+j][n=m = m_super+mt*16+p]
  bf16x8 bh[2][2], bl[2][2];
#pragma unroll
  for (int mt = 0; mt < 2; ++mt)
#pragma unroll
    for (int kst = 0; kst < 2; ++kst) {
      const size_t off = (size_t)nh * 4096 + (m_super + mt * 16 + p) * 64 + kst * 32 + q * 8;
      bh[mt][kst] = *(const bf16x8*)(kvh + off);      // 16B aligned dwordx4
      bl[mt][kst] = *(const bf16x8*)(kvl + off);
    }
  // resident ksum: lane's d-runs
  float ksr[2][8];
#pragma unroll
  for (int kst = 0; kst < 2; ++kst) {
    const float* kp = ksumg + (size_t)nh * 64 + kst * 32 + q * 8;
    float4 a = *(const float4*)(kp), b = *(const float4*)(kp + 4);
    ksr[kst][0]=a.x; ksr[kst][1]=a.y; ksr[kst][2]=a.z; ksr[kst][3]=a.w;
    ksr[kst][4]=b.x; ksr[kst][5]=b.y; ksr[kst][6]=b.z; ksr[kst][7]=b.w;
  }

  for (int lt = 0; lt < rows_pb / 2 / 16; ++lt) {     // 8 ltiles of 16 rows
    const int l0 = row_base + lt * 16;
    f32x4 acc[2] = {};
    float zpart = 0.f;

#pragma unroll
    for (int kst = 0; kst < 2; ++kst) {
      // A frag: phi(Q)[l = l0+p][d = kst*32+q*8+j] — contiguous 8 floats
      const float* qp = qbase + (size_t)(l0 + p) * RS + kst * 32 + q * 8;
      float4 f0 = *(const float4*)(qp), f1 = *(const float4*)(qp + 4);
      float f[8] = {f0.x, f0.y, f0.z, f0.w, f1.x, f1.y, f1.z, f1.w};
      bf16x8 ah, al;
#pragma unroll
      for (int j = 0; j < 8; ++j) {
        f[j] = phi(f[j]);
        short hi, lo; split2(f[j], hi, lo);
        ah[j] = hi; al[j] = lo;
        zpart += f[j] * ksr[kst][j];
      }
#pragma unroll
      for (int mt = 0; mt < 2; ++mt) {
        acc[mt] = MFMA16(ah, bh[mt][kst], acc[mt], 0, 0, 0);
        acc[mt] = MFMA16(ah, bl[mt][kst], acc[mt], 0, 0, 0);
        acc[mt] = MFMA16(al, bh[mt][kst], acc[mt], 0, 0, 0);
      }
    }

    // z for row l0+(lane&15): combine quads' d-subsets
    zpart += __shfl_xor(zpart, 16, 64);
    zpart += __shfl_xor(zpart, 32, 64);
    const float z = 1.0f / (zpart + 1e-6f);
    // move z into D layout: D lane needs rows l0 + q*4 + r
    float zr[4];
#pragma unroll
    for (int r = 0; r < 4; ++r) zr[r] = __shfl(z, q * 4 + r, 64);

#pragma unroll
    for (int mt = 0; mt < 2; ++mt) {
      const int col = m_super + mt * 16 + p;
#pragma unroll
      for (int r = 0; r < 4; ++r) {
        const int row = l0 + q * 4 + r;
        out[((size_t)nh * LL + row) * DD + col] = acc[mt][r] * zr[r];
      }
    }
  }
}

extern "C" void kernel_launch(void* const* d_in, const int* in_sizes, int n_in,
                              void* d_out, int out_size, void* d_ws, size_t ws_size,
                              hipStream_t stream)
{
  const float* Q = (const float*)d_in[0];
  const float* K = (const float*)d_in[1];
  const float* V = (const float*)d_in[2];
  float* out = (float*)d_out;

  int sch = 32;
  while (sch > 1) {
    size_t need = (size_t)NH * sch * KV_ELEMS * 4     // partials
                + (size_t)NH * 4096 * 2 * 2           // kvh + kvl (bf16)
                + (size_t)NH * 64 * 4;                // ksum
    if (need <= ws_size) break;
    sch >>= 1;
  }
  float* part = (float*)d_ws;
  short* kvh  = (short*)((char*)d_ws + (size_t)NH * sch * KV_ELEMS * 4);
  short* kvl  = kvh + (size_t)NH * 4096;
  float* ksum = (float*)(kvl + (size_t)NH * 4096);

  hipLaunchKernelGGL(kv_partial_kernel, dim3(NH * sch), dim3(256), 0, stream,
                     K, V, part, sch);
  hipLaunchKernelGGL(kv_reduce_kernel, dim3(NH * 17), dim3(256), 0, stream,
                     part, kvh, kvl, ksum, sch);
  hipLaunchKernelGGL(attn_out_kernel, dim3(NH * CCH), dim3(256), 0, stream,
                     Q, kvh, kvl, ksum, out);
}

// Round 2
// 241.449 us; speedup vs baseline: 1.0696x; 1.0696x over previous
//
#include <hip/hip_runtime.h>
#include <hip/hip_bf16.h>

#define NN 4
#define LL 8192
#define HH 8
#define DD 64
#define NH 32                 // n*h combos
#define RS  (HH*DD)           // 512 floats per s row (all heads)
#define KV_ELEMS 4160         // 64x64 kv + ksum[64]
#define CCH 64                // C-kernel l-chunks per n -> 4*64 = 256 blocks

typedef __attribute__((ext_vector_type(8))) short bf16x8;   // 8 bf16 (4 VGPR)
typedef __attribute__((ext_vector_type(4))) float f32x4;

__device__ __forceinline__ float phi(float x) {
  // elu(x*temp) + 1 ; temp = 64^(-0.25)
  float t = x * 0.35355339059327373f;
  return t > 0.f ? t + 1.f : __expf(t);
}
__device__ __forceinline__ short f2bf(float x) {
  __hip_bfloat16 h = __float2bfloat16(x);                  // RN
  return (short)__builtin_bit_cast(unsigned short, h);
}
__device__ __forceinline__ float bf2f(short s) {
  __hip_bfloat16 h = __builtin_bit_cast(__hip_bfloat16, (unsigned short)s);
  return __bfloat162float(h);
}
__device__ __forceinline__ void split2(float x, short& hi, short& lo) {
  hi = f2bf(x);
  lo = f2bf(x - bf2f(hi));
}
#define MFMA16 __builtin_amdgcn_mfma_f32_16x16x32_bf16

// ---------------- Kernel A: partial kv[d][m] += phi(K)^T V, ALL 8 heads per block ----------
// v3: h-fused so global reads are fully CONTIGUOUS 2KB rows (fixes the DRAM
// page-locality cap that pinned both previous versions at ~1.25 TB/s).
// Compute is fp32 VALU outer-product (2.1 TFLOP total ~ 14 us at vector peak):
// thread owns (h = tid>>6, 8 d, 8 m) -> acc[8][8]; K/V staged natural-layout
// f32 in LDS (broadcast reads, <=2-way). No bf16 in A => better accuracy.
__global__ __launch_bounds__(512, 2) void kv_partial_kernel(
    const float* __restrict__ K, const float* __restrict__ V,
    float* __restrict__ part, int sch)
{
  const int n = blockIdx.x / sch, chunk = blockIdx.x % sch;
  const int tid = threadIdx.x;
  const int h  = tid >> 6;
  const int t6 = tid & 63;
  const int d0 = ((t6 >> 3) & 7) * 8;
  const int m0 = (t6 & 7) * 8;
  const int hc = h * 64;
  const int sr = tid >> 6, sc = (tid & 63) * 8;   // staging: row 0..7, col *8 floats
  const int rows_pb = LL / sch;
  const int nt = rows_pb / 8;                     // 8-row s-tiles

  const float* kbase = K + ((size_t)n * LL + (size_t)chunk * rows_pb) * RS;
  const float* vbase = V + ((size_t)n * LL + (size_t)chunk * rows_pb) * RS;

  __shared__ float kls[8][520];   // phi(K) rows, natural [s][h*64+d], pitch-pad
  __shared__ float vls[8][520];   // V rows

  float acc[8][8] = {};
  float ksacc[8] = {};            // ksum partial for this thread's 8 staged cols
  f32x4 kr[2], vr[2];

  auto loada = [&](int T) {
    const float* kp_ = kbase + ((size_t)T * 8 + sr) * RS + sc;
    const float* vp_ = vbase + ((size_t)T * 8 + sr) * RS + sc;
    kr[0] = *(const f32x4*)(kp_);     kr[1] = *(const f32x4*)(kp_ + 4);
    vr[0] = *(const f32x4*)(vp_);     vr[1] = *(const f32x4*)(vp_ + 4);
  };

  loada(0);
  for (int t = 0; t < nt; ++t) {
    // ---- stage: phi(K) + raw V, natural layout ----
    f32x4 kw0, kw1;
#pragma unroll
    for (int jj = 0; jj < 4; ++jj) {
      float f0 = phi(kr[0][jj]);
      float f1 = phi(kr[1][jj]);
      ksacc[jj]     += f0;
      ksacc[jj + 4] += f1;
      kw0[jj] = f0; kw1[jj] = f1;
    }
    *(f32x4*)&kls[sr][sc]     = kw0;
    *(f32x4*)&kls[sr][sc + 4] = kw1;
    *(f32x4*)&vls[sr][sc]     = vr[0];
    *(f32x4*)&vls[sr][sc + 4] = vr[1];
    __syncthreads();
    if (t + 1 < nt) loada(t + 1);        // overlap next loads with compute

    // ---- compute: 8 s-rows of outer product ----
#pragma unroll 2
    for (int s = 0; s < 8; ++s) {
      const f32x4 k0 = *(const f32x4*)&kls[s][hc + d0];
      const f32x4 k1 = *(const f32x4*)&kls[s][hc + d0 + 4];
      const f32x4 v0 = *(const f32x4*)&vls[s][hc + m0];
      const f32x4 v1 = *(const f32x4*)&vls[s][hc + m0 + 4];
#pragma unroll
      for (int i = 0; i < 4; ++i)
#pragma unroll
        for (int j = 0; j < 4; ++j) {
          acc[i][j]         = fmaf(k0[i], v0[j], acc[i][j]);
          acc[i][j + 4]     = fmaf(k0[i], v1[j], acc[i][j + 4]);
          acc[i + 4][j]     = fmaf(k1[i], v0[j], acc[i + 4][j]);
          acc[i + 4][j + 4] = fmaf(k1[i], v1[j], acc[i + 4][j + 4]);
        }
    }
    __syncthreads();
  }

  // ---- store partial kv (fp32, exact) ----
  float* po = part + ((size_t)blockIdx.x * 8 + h) * KV_ELEMS;
#pragma unroll
  for (int i = 0; i < 8; ++i) {
    f32x4 o0 = {acc[i][0], acc[i][1], acc[i][2], acc[i][3]};
    f32x4 o1 = {acc[i][4], acc[i][5], acc[i][6], acc[i][7]};
    *(f32x4*)&po[(d0 + i) * 64 + m0]     = o0;
    *(f32x4*)&po[(d0 + i) * 64 + m0 + 4] = o1;
  }

  // ---- ksum: per-thread col partials -> LDS reduce over the 8 staging rows ----
#pragma unroll
  for (int j = 0; j < 8; ++j) vls[sr][sc + j] = ksacc[j];
  __syncthreads();
  {
    float s = 0.f;
#pragma unroll
    for (int r = 0; r < 8; ++r) s += vls[r][tid];      // col = tid (0..511)
    part[((size_t)blockIdx.x * 8 + (tid >> 6)) * KV_ELEMS + 4096 + (tid & 63)] = s;
  }
}

// ---------------- Kernel B: reduce partials; emit kv m-major split hi/lo + ksum ----------------
__global__ __launch_bounds__(256) void kv_reduce_kernel(
    const float* __restrict__ part, short* __restrict__ kvh,
    short* __restrict__ kvl, float* __restrict__ ksum, int np)
{
  const int nh = blockIdx.x / 17;
  const int e  = (blockIdx.x % 17) * 256 + threadIdx.x;
  if (e >= KV_ELEMS) return;
  const int n = nh >> 3, hh = nh & 7;
  const float* pp = part + ((size_t)(n * np) * 8 + hh) * KV_ELEMS + e;
  float s = 0.f;
  for (int i = 0; i < np; ++i) s += pp[(size_t)i * 8 * KV_ELEMS];
  if (e < 4096) {
    const int d = e >> 6, m = e & 63;
    short hi, lo; split2(s, hi, lo);
    kvh[(size_t)nh * 4096 + m * 64 + d] = hi;     // m-major: C's B-frags read
    kvl[(size_t)nh * 4096 + m * 64 + d] = lo;     // contiguous d-runs
  } else {
    ksum[(size_t)nh * 64 + (e - 4096)] = s;
  }
}

// ---------------- Kernel C: out[l][m] = z_l * (phi(Q) . kv) via MFMA, ALL 8 heads/block ------
// v3: h-fused. Block (512 thr) stages 16 CONTIGUOUS 2KB Q rows (all heads) as
// bf16 hi/lo planes; wave w = head w reads its d-contiguous A-frags (pitch 520
// -> uniform (p+q)%8 slot spread = minimum-cycle b128), kv B-frags register-
// resident (64 VGPR). 2-tile register prefetch hides HBM latency.
__global__ __launch_bounds__(512, 2) void attn_out_kernel(
    const float* __restrict__ Q, const short* __restrict__ kvh,
    const short* __restrict__ kvl, const float* __restrict__ ksumg,
    float* __restrict__ out)
{
  const int n = blockIdx.x / CCH, chunk = blockIdx.x % CCH;
  const int tid = threadIdx.x;
  const int w = tid >> 6, lane = tid & 63;            // w = head
  const int q = lane >> 4, p = lane & 15;
  const int nh = n * 8 + w;
  const int rows_pb = LL / CCH;                       // 128
  const int nt = rows_pb / 16;                        // 8 tiles of 16 rows
  const int l_base = chunk * rows_pb;
  const int sr = tid >> 5, sc = (tid & 31) * 16;      // staging: row 0..15, col *16

  const float* qbase = Q + (size_t)n * LL * RS;

  __shared__ short qh[16][520];                       // phiQ hi plane, natural [l][h*64+d]
  __shared__ short ql[16][520];                       // phiQ lo plane

  // resident B frags for this wave's head: B[k=d][m], m-major kv
  bf16x8 bh[4][2], bl[4][2];
#pragma unroll
  for (int mt = 0; mt < 4; ++mt)
#pragma unroll
    for (int kst = 0; kst < 2; ++kst) {
      const size_t off = (size_t)nh * 4096 + (size_t)(mt * 16 + p) * 64 + kst * 32 + q * 8;
      bh[mt][kst] = *(const bf16x8*)(kvh + off);
      bl[mt][kst] = *(const bf16x8*)(kvl + off);
    }
  float ksr[2][8];
#pragma unroll
  for (int kst = 0; kst < 2; ++kst) {
    const float* kp = ksumg + (size_t)nh * 64 + kst * 32 + q * 8;
    f32x4 a = *(const f32x4*)(kp), b = *(const f32x4*)(kp + 4);
    ksr[kst][0]=a[0]; ksr[kst][1]=a[1]; ksr[kst][2]=a[2]; ksr[kst][3]=a[3];
    ksr[kst][4]=b[0]; ksr[kst][5]=b[1]; ksr[kst][6]=b[2]; ksr[kst][7]=b[3];
  }

  f32x4 qa[4], qb[4];
  auto loadq = [&](f32x4* R, int T) {
    const float* qp_ = qbase + (size_t)(l_base + T * 16 + sr) * RS + sc;
    R[0] = *(const f32x4*)(qp_);      R[1] = *(const f32x4*)(qp_ + 4);
    R[2] = *(const f32x4*)(qp_ + 8);  R[3] = *(const f32x4*)(qp_ + 12);
  };

  auto cbody = [&](const f32x4* R, int T) {
    // ---- stage: phi + hi/lo split, natural layout ----
    bf16x8 hv0, hv1, lv0, lv1;
#pragma unroll
    for (int r = 0; r < 2; ++r)
#pragma unroll
      for (int jj = 0; jj < 4; ++jj) {
        float f = phi(R[r][jj]);
        short hs, ls; split2(f, hs, ls);
        hv0[r * 4 + jj] = hs; lv0[r * 4 + jj] = ls;
      }
#pragma unroll
    for (int r = 0; r < 2; ++r)
#pragma unroll
      for (int jj = 0; jj < 4; ++jj) {
        float f = phi(R[r + 2][jj]);
        short hs, ls; split2(f, hs, ls);
        hv1[r * 4 + jj] = hs; lv1[r * 4 + jj] = ls;
      }
    *(bf16x8*)&qh[sr][sc]     = hv0;  *(bf16x8*)&qh[sr][sc + 8] = hv1;
    *(bf16x8*)&ql[sr][sc]     = lv0;  *(bf16x8*)&ql[sr][sc + 8] = lv1;
    __syncthreads();

    // ---- compute: A-frags (d-contiguous), z, 24 MFMA, scaled store ----
    f32x4 acc[4] = {};
    float zp = 0.f;
    bf16x8 ah[2], al[2];
#pragma unroll
    for (int kst = 0; kst < 2; ++kst) {
      const int cc = w * 64 + kst * 32 + q * 8;
      ah[kst] = *(const bf16x8*)&qh[p][cc];
      al[kst] = *(const bf16x8*)&ql[p][cc];
#pragma unroll
      for (int j = 0; j < 8; ++j)
        zp += (bf2f(ah[kst][j]) + bf2f(al[kst][j])) * ksr[kst][j];
    }
#pragma unroll
    for (int kst = 0; kst < 2; ++kst)
#pragma unroll
      for (int mt = 0; mt < 4; ++mt) {
        acc[mt] = MFMA16(ah[kst], bh[mt][kst], acc[mt], 0, 0, 0);
        acc[mt] = MFMA16(ah[kst], bl[mt][kst], acc[mt], 0, 0, 0);
        acc[mt] = MFMA16(al[kst], bh[mt][kst], acc[mt], 0, 0, 0);
      }
    zp += __shfl_xor(zp, 16, 64);
    zp += __shfl_xor(zp, 32, 64);
    const float z = 1.0f / (zp + 1e-6f);
    float zr[4];
#pragma unroll
    for (int r = 0; r < 4; ++r) zr[r] = __shfl(z, q * 4 + r, 64);

    const int l0 = l_base + T * 16;
#pragma unroll
    for (int mt = 0; mt < 4; ++mt)
#pragma unroll
      for (int r = 0; r < 4; ++r)
        out[((size_t)nh * LL + l0 + q * 4 + r) * DD + mt * 16 + p] = acc[mt][r] * zr[r];
    __syncthreads();
  };

  loadq(qa, 0);
  for (int t = 0; t < nt; t += 2) {        // nt = 8 (even)
    loadq(qb, t + 1);
    cbody(qa, t);
    if (t + 2 < nt) loadq(qa, t + 2);
    cbody(qb, t + 1);
  }
}

extern "C" void kernel_launch(void* const* d_in, const int* in_sizes, int n_in,
                              void* d_out, int out_size, void* d_ws, size_t ws_size,
                              hipStream_t stream)
{
  const float* Q = (const float*)d_in[0];
  const float* K = (const float*)d_in[1];
  const float* V = (const float*)d_in[2];
  float* out = (float*)d_out;

  int sch = 64;                                        // s-chunks per n
  while (sch > 4) {
    size_t need = (size_t)NN * sch * 8 * KV_ELEMS * 4  // partials
                + (size_t)NH * 4096 * 2 * 2            // kvh + kvl (bf16)
                + (size_t)NH * 64 * 4;                 // ksum
    if (need <= ws_size) break;
    sch >>= 1;
  }
  float* part = (float*)d_ws;
  short* kvh  = (short*)((char*)d_ws + (size_t)NN * sch * 8 * KV_ELEMS * 4);
  short* kvl  = kvh + (size_t)NH * 4096;
  float* ksum = (float*)(kvl + (size_t)NH * 4096);

  hipLaunchKernelGGL(kv_partial_kernel, dim3(NN * sch), dim3(512), 0, stream,
                     K, V, part, sch);
  hipLaunchKernelGGL(kv_reduce_kernel, dim3(NH * 17), dim3(256), 0, stream,
                     part, kvh, kvl, ksum, sch);
  hipLaunchKernelGGL(attn_out_kernel, dim3(NN * CCH), dim3(512), 0, stream,
                     Q, kvh, kvl, ksum, out);
}